// Round 6
// baseline (107.296 us; speedup 1.0000x reference)
//
#include <hip/hip_runtime.h>
#include <hip/hip_bf16.h>
#include <math.h>
#include <string.h>

#define NB 8
#define NC 256
#define HWSZ 1024
#define NHEAD 8
#define DHEAD 32
#define NGRP 32
#define CPG 8
#define EPSV 1e-5f

typedef float f32x4 __attribute__((ext_vector_type(4)));
typedef short bf16x8 __attribute__((ext_vector_type(8)));
typedef short bf16x4 __attribute__((ext_vector_type(4)));

__device__ __forceinline__ unsigned pk2(float a, float b) {
    __hip_bfloat162 h = __float22bfloat162_rn(make_float2(a, b));
    unsigned r;
    memcpy(&r, &h, sizeof(r));
    return r;
}
__device__ __forceinline__ unsigned short f2bf(float x) {
    __hip_bfloat16 h = __float2bfloat16(x);
    unsigned short r;
    memcpy(&r, &h, sizeof(r));
    return r;
}

// ---------------- GroupNorm stats ----------------
__global__ void gn_stats_kernel(const float* __restrict__ xq,
                                const float* __restrict__ xkv,
                                float* __restrict__ stats) {
    int idx = blockIdx.x;            // which*256 + b*32 + g
    int which = idx >> 8;
    int b = (idx >> 5) & 7;
    int g = idx & 31;
    const float* x = which ? xkv : xq;
    const float4* xb = (const float4*)(x + ((size_t)(b * NC + g * CPG)) * HWSZ);
    float s = 0.f, ss = 0.f;
    for (int i = threadIdx.x; i < (CPG * HWSZ) / 4; i += 256) {
        float4 v = xb[i];
        s += v.x + v.y + v.z + v.w;
        ss += v.x * v.x + v.y * v.y + v.z * v.z + v.w * v.w;
    }
    #pragma unroll
    for (int off = 32; off > 0; off >>= 1) {
        s += __shfl_down(s, off);
        ss += __shfl_down(ss, off);
    }
    __shared__ float red[8];
    int wid = threadIdx.x >> 6;
    if ((threadIdx.x & 63) == 0) { red[wid * 2] = s; red[wid * 2 + 1] = ss; }
    __syncthreads();
    if (threadIdx.x == 0) {
        float S = red[0] + red[2] + red[4] + red[6];
        float SS = red[1] + red[3] + red[5] + red[7];
        float mean = S * (1.f / (CPG * HWSZ));
        float var = SS * (1.f / (CPG * HWSZ)) - mean * mean;
        stats[idx * 2] = mean;
        stats[idx * 2 + 1] = rsqrtf(var + EPSV);
    }
}

// ---------------- Weight convert: fp32 [o][c] -> bf16 [o][c]; Wq pre-scaled ----
__global__ void wconv_kernel(const float* __restrict__ Wq,
                             const float* __restrict__ Wkv,
                             const float* __restrict__ Wout,
                             unsigned short* __restrict__ wqb,
                             unsigned short* __restrict__ wkvb,
                             unsigned short* __restrict__ woutb) {
    int gid = blockIdx.x * 256 + threadIdx.x;   // 32768 threads, 8 floats each
    int i0 = gid * 8;
    const float* src; unsigned short* dst; int off; float sc = 1.f;
    if (i0 < 65536)       { src = Wq;   dst = wqb;   off = i0;          sc = 0.0625f * 1.44269504088896f; }
    else if (i0 < 196608) { src = Wkv;  dst = wkvb;  off = i0 - 65536; }
    else                  { src = Wout; dst = woutb; off = i0 - 196608; }
    float4 v0 = *(const float4*)&src[off];
    float4 v1 = *(const float4*)&src[off + 4];
    uint4 o;
    o.x = pk2(v0.x * sc, v0.y * sc); o.y = pk2(v0.z * sc, v0.w * sc);
    o.z = pk2(v1.x * sc, v1.y * sc); o.w = pk2(v1.z * sc, v1.w * sc);
    *(uint4*)&dst[off] = o;
}

// ---------------- Norm + bf16 + transpose: x fp32 [b][c][p] -> xn bf16 [b][p][c] ----
__global__ __launch_bounds__(256) void norm_t_kernel(
        const float* __restrict__ xq, const float* __restrict__ xkv,
        const float* __restrict__ stats,
        const float* __restrict__ sq, const float* __restrict__ bq,
        const float* __restrict__ skv, const float* __restrict__ bkv,
        unsigned short* __restrict__ xnq, unsigned short* __restrict__ xnkv) {
    __shared__ unsigned short T[64][72];   // [p][c], 144B rows
    const int bz = blockIdx.z;             // which*8 + b
    const int which = bz >> 3, b = bz & 7;
    const int c0 = blockIdx.y * 64, p0 = blockIdx.x * 64;
    const float* x  = which ? xkv : xq;
    const float* sc = which ? skv : sq;
    const float* bi = which ? bkv : bq;
    const float* st = stats + ((size_t)which * 256 + b * 32) * 2;
    const int tid = threadIdx.x;
    const int cb = tid >> 4, pb = tid & 15;
    float mm[4][4];
    #pragma unroll
    for (int u = 0; u < 4; ++u) {
        int c = c0 + cb * 4 + u;
        float4 v = *(const float4*)&x[((size_t)b * NC + c) * HWSZ + p0 + pb * 4];
        int gg = c >> 3;
        float mean = st[gg * 2], rstd = st[gg * 2 + 1];
        float a = rstd * sc[c];
        float bbv = bi[c] - mean * a;
        mm[u][0] = v.x * a + bbv; mm[u][1] = v.y * a + bbv;
        mm[u][2] = v.z * a + bbv; mm[u][3] = v.w * a + bbv;
    }
    #pragma unroll
    for (int v = 0; v < 4; ++v) {
        uint2 s2;
        s2.x = pk2(mm[0][v], mm[1][v]);
        s2.y = pk2(mm[2][v], mm[3][v]);
        *(uint2*)&T[pb * 4 + v][cb * 4] = s2;
    }
    __syncthreads();
    unsigned short* dst = (which ? xnkv : xnq) + (size_t)b * HWSZ * NC;
    #pragma unroll
    for (int it = 0; it < 2; ++it) {
        int i = tid + it * 256;
        int row = i >> 3, seg = i & 7;
        *(uint4*)&dst[(size_t)(p0 + row) * NC + c0 + seg * 8] = *(const uint4*)&T[row][seg * 8];
    }
}

// ---------------- MFMA GEMM over K=256, 64x64 tile, 4 waves ----------------
// MODE 0: Q  = Wq(A) x xnq(B)  -> qbuf bf16 [b][n][p][d]
// MODE 1: KV = Wkv(A) x xnkv(B)-> kbuf [b][n][p][d] (waves 0,1) / vbuf [b][n][d][p] (waves 2,3)
// MODE 2: OUT = obuf(A, rows p) x Wout(B, rows o) -> f32 d_out + bias + residual
template<int MODE>
__global__ __launch_bounds__(256) void gemm_kernel(
        const unsigned short* __restrict__ Abase,
        const unsigned short* __restrict__ Bbase,
        const float* __restrict__ bias_out,
        const float* __restrict__ resid,
        void* __restrict__ out0, void* __restrict__ out1) {
    __shared__ unsigned short As[64 * 256];
    __shared__ unsigned short Bs[64 * 256];
    const int tid = threadIdx.x;
    const int l16 = tid & 15, g = (tid >> 4) & 3, w = tid >> 6;
    const int o0 = blockIdx.y * 64;
    const size_t prow0 = (size_t)blockIdx.x * 64;
    const unsigned short* Asrc = (MODE < 2) ? (Abase + (size_t)o0 * NC) : (Abase + prow0 * NC);
    const unsigned short* Bsrc = (MODE < 2) ? (Bbase + prow0 * NC) : (Bbase + (size_t)o0 * NC);
    #pragma unroll
    for (int it = 0; it < 8; ++it) {
        int idx = tid + it * 256;
        int row = idx >> 5, seg = idx & 31;
        int ds = row * 256 + ((seg ^ (row & 7)) << 3);   // XOR-swizzled 16B units
        *(uint4*)&As[ds] = *(const uint4*)&Asrc[(size_t)row * NC + seg * 8];
        *(uint4*)&Bs[ds] = *(const uint4*)&Bsrc[(size_t)row * NC + seg * 8];
    }
    __syncthreads();
    f32x4 acc[4] = {};
    const int abase = (w * 16 + l16) * 256;
    const int asw = l16 & 7;
    #pragma unroll
    for (int kk = 0; kk < 8; ++kk) {
        const int koff = ((kk * 4 + g) ^ asw) << 3;
        bf16x8 a = *(const bf16x8*)&As[abase + koff];
        #pragma unroll
        for (int j = 0; j < 4; ++j) {
            bf16x8 b = *(const bf16x8*)&Bs[(j * 16 + l16) * 256 + koff];
            acc[j] = __builtin_amdgcn_mfma_f32_16x16x32_bf16(a, b, acc[j], 0, 0, 0);
        }
    }
    const int b = (int)(prow0 >> 10);
    const int pp = (int)(prow0 & 1023);
    if (MODE == 0) {
        int ob_ = o0 + 16 * w + 4 * g;
        int n = ob_ >> 5, d0 = ob_ & 31;
        unsigned short* dst = (unsigned short*)out0 + ((size_t)(b * NHEAD + n) * HWSZ) * DHEAD + d0;
        #pragma unroll
        for (int j = 0; j < 4; ++j) {
            int p = pp + 16 * j + l16;
            uint2 st;
            st.x = pk2(acc[j][0], acc[j][1]);
            st.y = pk2(acc[j][2], acc[j][3]);
            *(uint2*)&dst[(size_t)p * DHEAD] = st;
        }
    } else if (MODE == 1) {
        int n = o0 >> 6;
        int d0 = 16 * (w & 1) + 4 * g;
        if (w < 2) {   // K
            unsigned short* dst = (unsigned short*)out0 + ((size_t)(b * NHEAD + n) * HWSZ) * DHEAD + d0;
            #pragma unroll
            for (int j = 0; j < 4; ++j) {
                int p = pp + 16 * j + l16;
                uint2 st;
                st.x = pk2(acc[j][0], acc[j][1]);
                st.y = pk2(acc[j][2], acc[j][3]);
                *(uint2*)&dst[(size_t)p * DHEAD] = st;
            }
        } else {       // V -> [b][n][d][p]
            unsigned short* dst = (unsigned short*)out1 + ((size_t)(b * NHEAD + n) * DHEAD + d0) * HWSZ;
            #pragma unroll
            for (int j = 0; j < 4; ++j) {
                int p = pp + 16 * j + l16;
                #pragma unroll
                for (int r = 0; r < 4; ++r)
                    dst[(size_t)r * HWSZ + p] = f2bf(acc[j][r]);
            }
        }
    } else {
        int p_b = pp + 16 * w + 4 * g;
        #pragma unroll
        for (int j = 0; j < 4; ++j) {
            int o = o0 + 16 * j + l16;
            float bo = bias_out[o];
            size_t off = ((size_t)b * NC + o) * HWSZ + p_b;
            float4 rs = *(const float4*)&resid[off];
            float4 vst = make_float4(acc[j][0] + bo + rs.x, acc[j][1] + bo + rs.y,
                                     acc[j][2] + bo + rs.z, acc[j][3] + bo + rs.w);
            *(float4*)&((float*)out0)[off] = vst;
        }
    }
}

// ---------------- MFMA flash attention, zero-LDS ----------------
// P never leaves registers: PV uses a k-permutation sigma(g,e) = {4g..4g+3,
// 16+4g..16+4g+3} applied to BOTH operands (any bijective k-perm on A and B
// leaves the MFMA dot-product sum invariant). B-frag = packed exp'd scores
// exactly as born from the QK^T D-fragment; A-frag = V read with the same
// sigma (two 8B loads per row).
__global__ __launch_bounds__(256) void attn_mfma_kernel(
        const unsigned short* __restrict__ qb,
        const unsigned short* __restrict__ kb,
        const unsigned short* __restrict__ vb,
        unsigned short* __restrict__ ob) {
    const int tid = threadIdx.x;
    const int lane = tid & 63;
    const int l16 = lane & 15, g = lane >> 4;
    const int bn = blockIdx.y;
    const int qp = blockIdx.x * 64 + (tid >> 6) * 16 + l16;

    bf16x8 qf = *(const bf16x8*)(qb + ((size_t)bn * HWSZ + qp) * DHEAD + g * 8);
    const unsigned short* kbase = kb + (size_t)bn * HWSZ * DHEAD + (size_t)l16 * DHEAD + g * 8;
    const unsigned short* v_lo = vb + (size_t)bn * DHEAD * HWSZ + (size_t)l16 * HWSZ + 4 * g;
    const unsigned short* v_hi = v_lo + 16 * HWSZ;

    f32x4 acc0 = {0.f, 0.f, 0.f, 0.f}, acc1 = {0.f, 0.f, 0.f, 0.f};
    float m = -INFINITY, l = 0.f;

    for (int kt = 0; kt < 32; ++kt) {
        const unsigned short* kp = kbase + kt * 32 * DHEAD;
        bf16x8 kfa = *(const bf16x8*)kp;
        bf16x8 kfb = *(const bf16x8*)(kp + 16 * DHEAD);
        // V fragments (independent of softmax chain; sigma-permuted k order)
        bf16x4 va_l = *(const bf16x4*)(v_lo + kt * 32);
        bf16x4 va_h = *(const bf16x4*)(v_lo + kt * 32 + 16);
        bf16x4 vb_l = *(const bf16x4*)(v_hi + kt * 32);
        bf16x4 vb_h = *(const bf16x4*)(v_hi + kt * 32 + 16);
        bf16x8 va  = __builtin_shufflevector(va_l, va_h, 0, 1, 2, 3, 4, 5, 6, 7);
        bf16x8 vb8 = __builtin_shufflevector(vb_l, vb_h, 0, 1, 2, 3, 4, 5, 6, 7);

        f32x4 z = {0.f, 0.f, 0.f, 0.f};
        f32x4 s0 = __builtin_amdgcn_mfma_f32_16x16x32_bf16(kfa, qf, z, 0, 0, 0);
        f32x4 s1 = __builtin_amdgcn_mfma_f32_16x16x32_bf16(kfb, qf, z, 0, 0, 0);

        float tm = fmaxf(fmaxf(fmaxf(s0[0], s0[1]), fmaxf(s0[2], s0[3])),
                         fmaxf(fmaxf(s1[0], s1[1]), fmaxf(s1[2], s1[3])));
        tm = fmaxf(tm, __shfl_xor(tm, 16, 64));
        tm = fmaxf(tm, __shfl_xor(tm, 32, 64));
        // defer-max (T13): only rescale when the tile max grew past m+8
        if (!__all(tm <= m + 8.f)) {
            float mnew = fmaxf(m, tm);
            float corr = __builtin_amdgcn_exp2f(m - mnew);  // first tile: 2^-inf = 0
            acc0 *= corr; acc1 *= corr; l *= corr;
            m = mnew;
        }
        float p00 = __builtin_amdgcn_exp2f(s0[0] - m), p01 = __builtin_amdgcn_exp2f(s0[1] - m);
        float p02 = __builtin_amdgcn_exp2f(s0[2] - m), p03 = __builtin_amdgcn_exp2f(s0[3] - m);
        float p10 = __builtin_amdgcn_exp2f(s1[0] - m), p11 = __builtin_amdgcn_exp2f(s1[1] - m);
        float p12 = __builtin_amdgcn_exp2f(s1[2] - m), p13 = __builtin_amdgcn_exp2f(s1[3] - m);
        float lsum = ((p00 + p01) + (p02 + p03)) + ((p10 + p11) + (p12 + p13));
        lsum += __shfl_xor(lsum, 16, 64);
        lsum += __shfl_xor(lsum, 32, 64);
        l += lsum;

        // B-frag: keys in sigma order, straight from registers
        uint4 pw;
        pw.x = pk2(p00, p01); pw.y = pk2(p02, p03);
        pw.z = pk2(p10, p11); pw.w = pk2(p12, p13);
        bf16x8 pf;
        memcpy(&pf, &pw, sizeof(pf));

        acc0 = __builtin_amdgcn_mfma_f32_16x16x32_bf16(va,  pf, acc0, 0, 0, 0);
        acc1 = __builtin_amdgcn_mfma_f32_16x16x32_bf16(vb8, pf, acc1, 0, 0, 0);
    }
    float invl = 1.f / l;
    const int b = bn >> 3, n = bn & 7;
    unsigned short* dst = ob + ((size_t)b * HWSZ + qp) * NC + n * DHEAD;
    uint2 st0, st1;
    st0.x = pk2(acc0[0] * invl, acc0[1] * invl);
    st0.y = pk2(acc0[2] * invl, acc0[3] * invl);
    st1.x = pk2(acc1[0] * invl, acc1[1] * invl);
    st1.y = pk2(acc1[2] * invl, acc1[3] * invl);
    *(uint2*)&dst[4 * g]      = st0;
    *(uint2*)&dst[16 + 4 * g] = st1;
}

extern "C" void kernel_launch(void* const* d_in, const int* in_sizes, int n_in,
                              void* d_out, int out_size, void* d_ws, size_t ws_size,
                              hipStream_t stream) {
    const float* input_q  = (const float*)d_in[0];
    const float* input_kv = (const float*)d_in[1];
    const float* gq_scale = (const float*)d_in[2];
    const float* gq_bias  = (const float*)d_in[3];
    const float* gkv_scale = (const float*)d_in[4];
    const float* gkv_bias  = (const float*)d_in[5];
    const float* Wq   = (const float*)d_in[6];
    const float* Wkv  = (const float*)d_in[7];
    const float* Wout = (const float*)d_in[8];
    const float* bout = (const float*)d_in[9];
    float* out = (float*)d_out;

    char* ws = (char*)d_ws;
    float* stats = (float*)ws;                                    // 8 KB
    unsigned short* wqb   = (unsigned short*)(ws + 16384);        // 128 KB
    unsigned short* wkvb  = (unsigned short*)(ws + 16384 + 131072);        // 256 KB
    unsigned short* woutb = (unsigned short*)(ws + 16384 + 131072 + 262144); // 128 KB
    const size_t MB = 1024 * 1024;
    unsigned short* xnq  = (unsigned short*)(ws + 1 * MB);   // 4 MB  [b][p][c]
    unsigned short* xnkv = (unsigned short*)(ws + 5 * MB);   // 4 MB
    unsigned short* qbuf = (unsigned short*)(ws + 9 * MB);   // 4 MB  [b][n][p][d]
    unsigned short* kbuf = (unsigned short*)(ws + 13 * MB);  // 4 MB  [b][n][p][d]
    unsigned short* vbuf = (unsigned short*)(ws + 17 * MB);  // 4 MB  [b][n][d][p]
    unsigned short* obuf = (unsigned short*)(ws + 21 * MB);  // 4 MB  [b][p][c]

    gn_stats_kernel<<<512, 256, 0, stream>>>(input_q, input_kv, stats);
    wconv_kernel<<<128, 256, 0, stream>>>(Wq, Wkv, Wout, wqb, wkvb, woutb);
    norm_t_kernel<<<dim3(16, 4, 16), 256, 0, stream>>>(
        input_q, input_kv, stats, gq_scale, gq_bias, gkv_scale, gkv_bias, xnq, xnkv);
    gemm_kernel<0><<<dim3(128, 4), 256, 0, stream>>>(wqb, xnq, nullptr, nullptr, qbuf, nullptr);
    gemm_kernel<1><<<dim3(128, 8), 256, 0, stream>>>(wkvb, xnkv, nullptr, nullptr, kbuf, vbuf);
    attn_mfma_kernel<<<dim3(16, 64), 256, 0, stream>>>(qbuf, kbuf, vbuf, obuf);
    gemm_kernel<2><<<dim3(128, 4), 256, 0, stream>>>(obuf, woutb, bout, input_q, out, nullptr);
}

// Round 7
// 80.374 us; speedup vs baseline: 1.3350x; 1.3350x over previous
//
#include <hip/hip_runtime.h>
#include <hip/hip_bf16.h>
#include <math.h>
#include <string.h>

#define NB 8
#define NC 256
#define HWSZ 1024
#define NHEAD 8
#define DHEAD 32
#define NGRP 32
#define CPG 8
#define EPSV 1e-5f

typedef float f32x4 __attribute__((ext_vector_type(4)));
typedef short bf16x8 __attribute__((ext_vector_type(8)));

__device__ __forceinline__ unsigned pk2(float a, float b) {
    __hip_bfloat162 h = __float22bfloat162_rn(make_float2(a, b));
    unsigned r;
    memcpy(&r, &h, sizeof(r));
    return r;
}
__device__ __forceinline__ unsigned short f2bf(float x) {
    __hip_bfloat16 h = __float2bfloat16(x);
    unsigned short r;
    memcpy(&r, &h, sizeof(r));
    return r;
}

// ---------------- GroupNorm stats ----------------
__global__ void gn_stats_kernel(const float* __restrict__ xq,
                                const float* __restrict__ xkv,
                                float* __restrict__ stats) {
    int idx = blockIdx.x;            // which*256 + b*32 + g
    int which = idx >> 8;
    int b = (idx >> 5) & 7;
    int g = idx & 31;
    const float* x = which ? xkv : xq;
    const float4* xb = (const float4*)(x + ((size_t)(b * NC + g * CPG)) * HWSZ);
    float s = 0.f, ss = 0.f;
    for (int i = threadIdx.x; i < (CPG * HWSZ) / 4; i += 256) {
        float4 v = xb[i];
        s += v.x + v.y + v.z + v.w;
        ss += v.x * v.x + v.y * v.y + v.z * v.z + v.w * v.w;
    }
    #pragma unroll
    for (int off = 32; off > 0; off >>= 1) {
        s += __shfl_down(s, off);
        ss += __shfl_down(ss, off);
    }
    __shared__ float red[8];
    int wid = threadIdx.x >> 6;
    if ((threadIdx.x & 63) == 0) { red[wid * 2] = s; red[wid * 2 + 1] = ss; }
    __syncthreads();
    if (threadIdx.x == 0) {
        float S = red[0] + red[2] + red[4] + red[6];
        float SS = red[1] + red[3] + red[5] + red[7];
        float mean = S * (1.f / (CPG * HWSZ));
        float var = SS * (1.f / (CPG * HWSZ)) - mean * mean;
        stats[idx * 2] = mean;
        stats[idx * 2 + 1] = rsqrtf(var + EPSV);
    }
}

// ---------------- Weight convert: fp32 [o][c] -> bf16 [o][c]; Wq pre-scaled ----
__global__ void wconv_kernel(const float* __restrict__ Wq,
                             const float* __restrict__ Wkv,
                             const float* __restrict__ Wout,
                             unsigned short* __restrict__ wqb,
                             unsigned short* __restrict__ wkvb,
                             unsigned short* __restrict__ woutb) {
    int gid = blockIdx.x * 256 + threadIdx.x;   // 32768 threads, 8 floats each
    int i0 = gid * 8;
    const float* src; unsigned short* dst; int off; float sc = 1.f;
    if (i0 < 65536)       { src = Wq;   dst = wqb;   off = i0;          sc = 0.0625f * 1.44269504088896f; }
    else if (i0 < 196608) { src = Wkv;  dst = wkvb;  off = i0 - 65536; }
    else                  { src = Wout; dst = woutb; off = i0 - 196608; }
    float4 v0 = *(const float4*)&src[off];
    float4 v1 = *(const float4*)&src[off + 4];
    uint4 o;
    o.x = pk2(v0.x * sc, v0.y * sc); o.y = pk2(v0.z * sc, v0.w * sc);
    o.z = pk2(v1.x * sc, v1.y * sc); o.w = pk2(v1.z * sc, v1.w * sc);
    *(uint4*)&dst[off] = o;
}

// ---------------- Norm + bf16 + transpose: x fp32 [b][c][p] -> xn bf16 [b][p][c] ----
__global__ __launch_bounds__(256) void norm_t_kernel(
        const float* __restrict__ xq, const float* __restrict__ xkv,
        const float* __restrict__ stats,
        const float* __restrict__ sq, const float* __restrict__ bq,
        const float* __restrict__ skv, const float* __restrict__ bkv,
        unsigned short* __restrict__ xnq, unsigned short* __restrict__ xnkv) {
    __shared__ unsigned short T[64][72];   // [p][c], 144B rows
    const int bz = blockIdx.z;             // which*8 + b
    const int which = bz >> 3, b = bz & 7;
    const int c0 = blockIdx.y * 64, p0 = blockIdx.x * 64;
    const float* x  = which ? xkv : xq;
    const float* sc = which ? skv : sq;
    const float* bi = which ? bkv : bq;
    const float* st = stats + ((size_t)which * 256 + b * 32) * 2;
    const int tid = threadIdx.x;
    const int cb = tid >> 4, pb = tid & 15;
    float mm[4][4];
    #pragma unroll
    for (int u = 0; u < 4; ++u) {
        int c = c0 + cb * 4 + u;
        float4 v = *(const float4*)&x[((size_t)b * NC + c) * HWSZ + p0 + pb * 4];
        int gg = c >> 3;
        float mean = st[gg * 2], rstd = st[gg * 2 + 1];
        float a = rstd * sc[c];
        float bbv = bi[c] - mean * a;
        mm[u][0] = v.x * a + bbv; mm[u][1] = v.y * a + bbv;
        mm[u][2] = v.z * a + bbv; mm[u][3] = v.w * a + bbv;
    }
    #pragma unroll
    for (int v = 0; v < 4; ++v) {
        uint2 s2;
        s2.x = pk2(mm[0][v], mm[1][v]);
        s2.y = pk2(mm[2][v], mm[3][v]);
        *(uint2*)&T[pb * 4 + v][cb * 4] = s2;
    }
    __syncthreads();
    unsigned short* dst = (which ? xnkv : xnq) + (size_t)b * HWSZ * NC;
    #pragma unroll
    for (int it = 0; it < 2; ++it) {
        int i = tid + it * 256;
        int row = i >> 3, seg = i & 7;
        *(uint4*)&dst[(size_t)(p0 + row) * NC + c0 + seg * 8] = *(const uint4*)&T[row][seg * 8];
    }
}

// ---------------- MFMA GEMM over K=256, 64x64 tile, 4 waves ----------------
// MODE 0: Q  = Wq(A) x xnq(B)  -> qbuf bf16 [b][n][p][d]
// MODE 1: KV = Wkv(A) x xnkv(B)-> kbuf [b][n][p][d] (waves 0,1) / vbuf sigma-permuted
// MODE 2: OUT = obuf(A, rows p) x Wout(B, rows o) -> f32 d_out + bias + residual
template<int MODE>
__global__ __launch_bounds__(256) void gemm_kernel(
        const unsigned short* __restrict__ Abase,
        const unsigned short* __restrict__ Bbase,
        const float* __restrict__ bias_out,
        const float* __restrict__ resid,
        void* __restrict__ out0, void* __restrict__ out1) {
    __shared__ unsigned short As[64 * 256];
    __shared__ unsigned short Bs[64 * 256];
    const int tid = threadIdx.x;
    const int l16 = tid & 15, g = (tid >> 4) & 3, w = tid >> 6;
    const int o0 = blockIdx.y * 64;
    const size_t prow0 = (size_t)blockIdx.x * 64;
    const unsigned short* Asrc = (MODE < 2) ? (Abase + (size_t)o0 * NC) : (Abase + prow0 * NC);
    const unsigned short* Bsrc = (MODE < 2) ? (Bbase + prow0 * NC) : (Bbase + (size_t)o0 * NC);
    #pragma unroll
    for (int it = 0; it < 8; ++it) {
        int idx = tid + it * 256;
        int row = idx >> 5, seg = idx & 31;
        int ds = row * 256 + ((seg ^ (row & 7)) << 3);   // XOR-swizzled 16B units
        *(uint4*)&As[ds] = *(const uint4*)&Asrc[(size_t)row * NC + seg * 8];
        *(uint4*)&Bs[ds] = *(const uint4*)&Bsrc[(size_t)row * NC + seg * 8];
    }
    __syncthreads();
    f32x4 acc[4] = {};
    const int abase = (w * 16 + l16) * 256;
    const int asw = l16 & 7;
    #pragma unroll
    for (int kk = 0; kk < 8; ++kk) {
        const int koff = ((kk * 4 + g) ^ asw) << 3;
        bf16x8 a = *(const bf16x8*)&As[abase + koff];
        #pragma unroll
        for (int j = 0; j < 4; ++j) {
            bf16x8 b = *(const bf16x8*)&Bs[(j * 16 + l16) * 256 + koff];
            acc[j] = __builtin_amdgcn_mfma_f32_16x16x32_bf16(a, b, acc[j], 0, 0, 0);
        }
    }
    const int b = (int)(prow0 >> 10);
    const int pp = (int)(prow0 & 1023);
    if (MODE == 0) {
        int ob_ = o0 + 16 * w + 4 * g;
        int n = ob_ >> 5, d0 = ob_ & 31;
        unsigned short* dst = (unsigned short*)out0 + ((size_t)(b * NHEAD + n) * HWSZ) * DHEAD + d0;
        #pragma unroll
        for (int j = 0; j < 4; ++j) {
            int p = pp + 16 * j + l16;
            uint2 st;
            st.x = pk2(acc[j][0], acc[j][1]);
            st.y = pk2(acc[j][2], acc[j][3]);
            *(uint2*)&dst[(size_t)p * DHEAD] = st;
        }
    } else if (MODE == 1) {
        int n = o0 >> 6;
        int d0 = 16 * (w & 1) + 4 * g;
        if (w < 2) {   // K
            unsigned short* dst = (unsigned short*)out0 + ((size_t)(b * NHEAD + n) * HWSZ) * DHEAD + d0;
            #pragma unroll
            for (int j = 0; j < 4; ++j) {
                int p = pp + 16 * j + l16;
                uint2 st;
                st.x = pk2(acc[j][0], acc[j][1]);
                st.y = pk2(acc[j][2], acc[j][3]);
                *(uint2*)&dst[(size_t)p * DHEAD] = st;
            }
        } else {
            // V -> [b][n][d][p'] with sigma-permuted key order within each
            // 32-key block: key k32 = 16*(j&1)+l16 stored at slot
            // 8*(l16>>2) + 4*(j&1) + (l16&3), so attention's PV A-fragment
            // (kslots 8g..8g+7) is one contiguous 16B load.
            unsigned short* dst = (unsigned short*)out1 + ((size_t)(b * NHEAD + n) * DHEAD + d0) * HWSZ;
            #pragma unroll
            for (int j = 0; j < 4; ++j) {
                int slot = ((l16 >> 2) << 3) + ((j & 1) << 2) + (l16 & 3);
                int p = pp + 32 * (j >> 1) + slot;
                #pragma unroll
                for (int r = 0; r < 4; ++r)
                    dst[(size_t)r * HWSZ + p] = f2bf(acc[j][r]);
            }
        }
    } else {
        int p_b = pp + 16 * w + 4 * g;
        #pragma unroll
        for (int j = 0; j < 4; ++j) {
            int o = o0 + 16 * j + l16;
            float bo = bias_out[o];
            size_t off = ((size_t)b * NC + o) * HWSZ + p_b;
            float4 rs = *(const float4*)&resid[off];
            float4 vst = make_float4(acc[j][0] + bo + rs.x, acc[j][1] + bo + rs.y,
                                     acc[j][2] + bo + rs.z, acc[j][3] + bo + rs.w);
            *(float4*)&((float*)out0)[off] = vst;
        }
    }
}

// ---------------- MFMA flash attention, zero-LDS, distance-2 pipeline ----------------
// P never leaves registers (sigma k-perm on both PV operands); V is stored
// sigma-permuted so the A-frag is one 16B load. Tiles kt+2's K/V loads are
// issued before tile kt's compute so VMEM latency hides under ~1 tile of
// compute x 4 co-resident waves.
__global__ __launch_bounds__(256) void attn_mfma_kernel(
        const unsigned short* __restrict__ qb,
        const unsigned short* __restrict__ kb,
        const unsigned short* __restrict__ vb,
        unsigned short* __restrict__ ob) {
    const int tid = threadIdx.x;
    const int lane = tid & 63;
    const int l16 = lane & 15, g = lane >> 4;
    const int bn = blockIdx.y;
    const int qp = blockIdx.x * 64 + (tid >> 6) * 16 + l16;

    bf16x8 qf = *(const bf16x8*)(qb + ((size_t)bn * HWSZ + qp) * DHEAD + g * 8);
    const unsigned short* kbase = kb + (size_t)bn * HWSZ * DHEAD + (size_t)l16 * DHEAD + g * 8;
    const unsigned short* v_lo = vb + (size_t)bn * DHEAD * HWSZ + (size_t)l16 * HWSZ + 8 * g;
    const unsigned short* v_hi = v_lo + 16 * HWSZ;

    f32x4 acc0 = {0.f, 0.f, 0.f, 0.f}, acc1 = {0.f, 0.f, 0.f, 0.f};
    float m = -INFINITY, l = 0.f;

#define LOADK_A(kt) (*(const bf16x8*)(kbase + (kt) * 32 * DHEAD))
#define LOADK_B(kt) (*(const bf16x8*)(kbase + (kt) * 32 * DHEAD + 16 * DHEAD))
#define LOADV_A(kt) (*(const bf16x8*)(v_lo + (kt) * 32))
#define LOADV_B(kt) (*(const bf16x8*)(v_hi + (kt) * 32))

    bf16x8 ka0 = LOADK_A(0), kb0 = LOADK_B(0), va0 = LOADV_A(0), vb0 = LOADV_B(0);
    bf16x8 ka1 = LOADK_A(1), kb1 = LOADK_B(1), va1 = LOADV_A(1), vb1 = LOADV_B(1);

    #pragma unroll
    for (int kt = 0; kt < 32; ++kt) {
        bf16x8 nka = ka1, nkb = kb1, nva = va1, nvb = vb1;
        if (kt + 2 < 32) {
            nka = LOADK_A(kt + 2); nkb = LOADK_B(kt + 2);
            nva = LOADV_A(kt + 2); nvb = LOADV_B(kt + 2);
        }

        f32x4 z = {0.f, 0.f, 0.f, 0.f};
        f32x4 s0 = __builtin_amdgcn_mfma_f32_16x16x32_bf16(ka0, qf, z, 0, 0, 0);
        f32x4 s1 = __builtin_amdgcn_mfma_f32_16x16x32_bf16(kb0, qf, z, 0, 0, 0);

        float tm = fmaxf(fmaxf(fmaxf(s0[0], s0[1]), fmaxf(s0[2], s0[3])),
                         fmaxf(fmaxf(s1[0], s1[1]), fmaxf(s1[2], s1[3])));
        tm = fmaxf(tm, __shfl_xor(tm, 16, 64));
        tm = fmaxf(tm, __shfl_xor(tm, 32, 64));
        // defer-max (T13): only rescale when the tile max grew past m+8
        if (!__all(tm <= m + 8.f)) {
            float mnew = fmaxf(m, tm);
            float corr = __builtin_amdgcn_exp2f(m - mnew);  // first tile: 2^-inf = 0
            acc0 *= corr; acc1 *= corr; l *= corr;
            m = mnew;
        }
        float p00 = __builtin_amdgcn_exp2f(s0[0] - m), p01 = __builtin_amdgcn_exp2f(s0[1] - m);
        float p02 = __builtin_amdgcn_exp2f(s0[2] - m), p03 = __builtin_amdgcn_exp2f(s0[3] - m);
        float p10 = __builtin_amdgcn_exp2f(s1[0] - m), p11 = __builtin_amdgcn_exp2f(s1[1] - m);
        float p12 = __builtin_amdgcn_exp2f(s1[2] - m), p13 = __builtin_amdgcn_exp2f(s1[3] - m);
        float lsum = ((p00 + p01) + (p02 + p03)) + ((p10 + p11) + (p12 + p13));
        lsum += __shfl_xor(lsum, 16, 64);
        lsum += __shfl_xor(lsum, 32, 64);
        l += lsum;

        // B-frag: keys in sigma order, straight from registers
        uint4 pw;
        pw.x = pk2(p00, p01); pw.y = pk2(p02, p03);
        pw.z = pk2(p10, p11); pw.w = pk2(p12, p13);
        bf16x8 pf;
        memcpy(&pf, &pw, sizeof(pf));

        acc0 = __builtin_amdgcn_mfma_f32_16x16x32_bf16(va0, pf, acc0, 0, 0, 0);
        acc1 = __builtin_amdgcn_mfma_f32_16x16x32_bf16(vb0, pf, acc1, 0, 0, 0);

        ka0 = ka1; kb0 = kb1; va0 = va1; vb0 = vb1;
        ka1 = nka; kb1 = nkb; va1 = nva; vb1 = nvb;
    }
#undef LOADK_A
#undef LOADK_B
#undef LOADV_A
#undef LOADV_B

    float invl = 1.f / l;
    const int b = bn >> 3, n = bn & 7;
    unsigned short* dst = ob + ((size_t)b * HWSZ + qp) * NC + n * DHEAD;
    uint2 st0, st1;
    st0.x = pk2(acc0[0] * invl, acc0[1] * invl);
    st0.y = pk2(acc0[2] * invl, acc0[3] * invl);
    st1.x = pk2(acc1[0] * invl, acc1[1] * invl);
    st1.y = pk2(acc1[2] * invl, acc1[3] * invl);
    *(uint2*)&dst[4 * g]      = st0;
    *(uint2*)&dst[16 + 4 * g] = st1;
}

extern "C" void kernel_launch(void* const* d_in, const int* in_sizes, int n_in,
                              void* d_out, int out_size, void* d_ws, size_t ws_size,
                              hipStream_t stream) {
    const float* input_q  = (const float*)d_in[0];
    const float* input_kv = (const float*)d_in[1];
    const float* gq_scale = (const float*)d_in[2];
    const float* gq_bias  = (const float*)d_in[3];
    const float* gkv_scale = (const float*)d_in[4];
    const float* gkv_bias  = (const float*)d_in[5];
    const float* Wq   = (const float*)d_in[6];
    const float* Wkv  = (const float*)d_in[7];
    const float* Wout = (const float*)d_in[8];
    const float* bout = (const float*)d_in[9];
    float* out = (float*)d_out;

    char* ws = (char*)d_ws;
    float* stats = (float*)ws;                                    // 8 KB
    unsigned short* wqb   = (unsigned short*)(ws + 16384);        // 128 KB
    unsigned short* wkvb  = (unsigned short*)(ws + 16384 + 131072);        // 256 KB
    unsigned short* woutb = (unsigned short*)(ws + 16384 + 131072 + 262144); // 128 KB
    const size_t MB = 1024 * 1024;
    unsigned short* xnq  = (unsigned short*)(ws + 1 * MB);   // 4 MB  [b][p][c]
    unsigned short* xnkv = (unsigned short*)(ws + 5 * MB);   // 4 MB
    unsigned short* qbuf = (unsigned short*)(ws + 9 * MB);   // 4 MB  [b][n][p][d]
    unsigned short* kbuf = (unsigned short*)(ws + 13 * MB);  // 4 MB  [b][n][p][d]
    unsigned short* vbuf = (unsigned short*)(ws + 17 * MB);  // 4 MB  [b][n][d][p'] sigma-permuted
    unsigned short* obuf = (unsigned short*)(ws + 21 * MB);  // 4 MB  [b][p][c]

    gn_stats_kernel<<<512, 256, 0, stream>>>(input_q, input_kv, stats);
    wconv_kernel<<<128, 256, 0, stream>>>(Wq, Wkv, Wout, wqb, wkvb, woutb);
    norm_t_kernel<<<dim3(16, 4, 16), 256, 0, stream>>>(
        input_q, input_kv, stats, gq_scale, gq_bias, gkv_scale, gkv_bias, xnq, xnkv);
    gemm_kernel<0><<<dim3(128, 4), 256, 0, stream>>>(wqb, xnq, nullptr, nullptr, qbuf, nullptr);
    gemm_kernel<1><<<dim3(128, 8), 256, 0, stream>>>(wkvb, xnkv, nullptr, nullptr, kbuf, vbuf);
    attn_mfma_kernel<<<dim3(16, 64), 256, 0, stream>>>(qbuf, kbuf, vbuf, obuf);
    gemm_kernel<2><<<dim3(128, 4), 256, 0, stream>>>(obuf, woutb, bout, input_q, out, nullptr);
}

// Round 8
// 79.771 us; speedup vs baseline: 1.3450x; 1.0076x over previous
//
#include <hip/hip_runtime.h>
#include <hip/hip_bf16.h>
#include <math.h>
#include <string.h>

#define NB 8
#define NC 256
#define HWSZ 1024
#define NHEAD 8
#define DHEAD 32
#define NGRP 32
#define CPG 8
#define EPSV 1e-5f

typedef float f32x4 __attribute__((ext_vector_type(4)));
typedef short bf16x8 __attribute__((ext_vector_type(8)));

__device__ __forceinline__ unsigned pk2(float a, float b) {
    __hip_bfloat162 h = __float22bfloat162_rn(make_float2(a, b));
    unsigned r;
    memcpy(&r, &h, sizeof(r));
    return r;
}
__device__ __forceinline__ unsigned short f2bf(float x) {
    __hip_bfloat16 h = __float2bfloat16(x);
    unsigned short r;
    memcpy(&r, &h, sizeof(r));
    return r;
}

// ---------------- GroupNorm stats ----------------
__global__ void gn_stats_kernel(const float* __restrict__ xq,
                                const float* __restrict__ xkv,
                                float* __restrict__ stats) {
    int idx = blockIdx.x;            // which*256 + b*32 + g
    int which = idx >> 8;
    int b = (idx >> 5) & 7;
    int g = idx & 31;
    const float* x = which ? xkv : xq;
    const float4* xb = (const float4*)(x + ((size_t)(b * NC + g * CPG)) * HWSZ);
    float s = 0.f, ss = 0.f;
    for (int i = threadIdx.x; i < (CPG * HWSZ) / 4; i += 256) {
        float4 v = xb[i];
        s += v.x + v.y + v.z + v.w;
        ss += v.x * v.x + v.y * v.y + v.z * v.z + v.w * v.w;
    }
    #pragma unroll
    for (int off = 32; off > 0; off >>= 1) {
        s += __shfl_down(s, off);
        ss += __shfl_down(ss, off);
    }
    __shared__ float red[8];
    int wid = threadIdx.x >> 6;
    if ((threadIdx.x & 63) == 0) { red[wid * 2] = s; red[wid * 2 + 1] = ss; }
    __syncthreads();
    if (threadIdx.x == 0) {
        float S = red[0] + red[2] + red[4] + red[6];
        float SS = red[1] + red[3] + red[5] + red[7];
        float mean = S * (1.f / (CPG * HWSZ));
        float var = SS * (1.f / (CPG * HWSZ)) - mean * mean;
        stats[idx * 2] = mean;
        stats[idx * 2 + 1] = rsqrtf(var + EPSV);
    }
}

// ---------------- Weight convert: fp32 [o][c] -> bf16 [o][c]; Wq pre-scaled ----
__global__ void wconv_kernel(const float* __restrict__ Wq,
                             const float* __restrict__ Wkv,
                             const float* __restrict__ Wout,
                             unsigned short* __restrict__ wqb,
                             unsigned short* __restrict__ wkvb,
                             unsigned short* __restrict__ woutb) {
    int gid = blockIdx.x * 256 + threadIdx.x;   // 32768 threads, 8 floats each
    int i0 = gid * 8;
    const float* src; unsigned short* dst; int off; float sc = 1.f;
    if (i0 < 65536)       { src = Wq;   dst = wqb;   off = i0;          sc = 0.0625f * 1.44269504088896f; }
    else if (i0 < 196608) { src = Wkv;  dst = wkvb;  off = i0 - 65536; }
    else                  { src = Wout; dst = woutb; off = i0 - 196608; }
    float4 v0 = *(const float4*)&src[off];
    float4 v1 = *(const float4*)&src[off + 4];
    uint4 o;
    o.x = pk2(v0.x * sc, v0.y * sc); o.y = pk2(v0.z * sc, v0.w * sc);
    o.z = pk2(v1.x * sc, v1.y * sc); o.w = pk2(v1.z * sc, v1.w * sc);
    *(uint4*)&dst[off] = o;
}

// ---------------- Norm + bf16 + transpose: x fp32 [b][c][p] -> xn bf16 [b][p][c] ----
__global__ __launch_bounds__(256) void norm_t_kernel(
        const float* __restrict__ xq, const float* __restrict__ xkv,
        const float* __restrict__ stats,
        const float* __restrict__ sq, const float* __restrict__ bq,
        const float* __restrict__ skv, const float* __restrict__ bkv,
        unsigned short* __restrict__ xnq, unsigned short* __restrict__ xnkv) {
    __shared__ unsigned short T[64][72];   // [p][c], 144B rows
    const int bz = blockIdx.z;             // which*8 + b
    const int which = bz >> 3, b = bz & 7;
    const int c0 = blockIdx.y * 64, p0 = blockIdx.x * 64;
    const float* x  = which ? xkv : xq;
    const float* sc = which ? skv : sq;
    const float* bi = which ? bkv : bq;
    const float* st = stats + ((size_t)which * 256 + b * 32) * 2;
    const int tid = threadIdx.x;
    const int cb = tid >> 4, pb = tid & 15;
    float mm[4][4];
    #pragma unroll
    for (int u = 0; u < 4; ++u) {
        int c = c0 + cb * 4 + u;
        float4 v = *(const float4*)&x[((size_t)b * NC + c) * HWSZ + p0 + pb * 4];
        int gg = c >> 3;
        float mean = st[gg * 2], rstd = st[gg * 2 + 1];
        float a = rstd * sc[c];
        float bbv = bi[c] - mean * a;
        mm[u][0] = v.x * a + bbv; mm[u][1] = v.y * a + bbv;
        mm[u][2] = v.z * a + bbv; mm[u][3] = v.w * a + bbv;
    }
    #pragma unroll
    for (int v = 0; v < 4; ++v) {
        uint2 s2;
        s2.x = pk2(mm[0][v], mm[1][v]);
        s2.y = pk2(mm[2][v], mm[3][v]);
        *(uint2*)&T[pb * 4 + v][cb * 4] = s2;
    }
    __syncthreads();
    unsigned short* dst = (which ? xnkv : xnq) + (size_t)b * HWSZ * NC;
    #pragma unroll
    for (int it = 0; it < 2; ++it) {
        int i = tid + it * 256;
        int row = i >> 3, seg = i & 7;
        *(uint4*)&dst[(size_t)(p0 + row) * NC + c0 + seg * 8] = *(const uint4*)&T[row][seg * 8];
    }
}

// ---------------- MFMA GEMM over K=256, 64x64 tile, 4 waves ----------------
// MODE 0: Q  = Wq(A) x xnq(B)  -> qbuf bf16 [b][n][p][d]
// MODE 1: KV = Wkv(A) x xnkv(B)-> kbuf [b][n][p][d] (waves 0,1) / vbuf sigma-permuted
// MODE 2: OUT = obuf(A, rows p) x Wout(B, rows o) -> f32 d_out + bias + residual
template<int MODE>
__global__ __launch_bounds__(256) void gemm_kernel(
        const unsigned short* __restrict__ Abase,
        const unsigned short* __restrict__ Bbase,
        const float* __restrict__ bias_out,
        const float* __restrict__ resid,
        void* __restrict__ out0, void* __restrict__ out1) {
    __shared__ unsigned short As[64 * 256];
    __shared__ unsigned short Bs[64 * 256];
    const int tid = threadIdx.x;
    const int l16 = tid & 15, g = (tid >> 4) & 3, w = tid >> 6;
    const int o0 = blockIdx.y * 64;
    const size_t prow0 = (size_t)blockIdx.x * 64;
    const unsigned short* Asrc = (MODE < 2) ? (Abase + (size_t)o0 * NC) : (Abase + prow0 * NC);
    const unsigned short* Bsrc = (MODE < 2) ? (Bbase + prow0 * NC) : (Bbase + (size_t)o0 * NC);
    #pragma unroll
    for (int it = 0; it < 8; ++it) {
        int idx = tid + it * 256;
        int row = idx >> 5, seg = idx & 31;
        int ds = row * 256 + ((seg ^ (row & 7)) << 3);   // XOR-swizzled 16B units
        *(uint4*)&As[ds] = *(const uint4*)&Asrc[(size_t)row * NC + seg * 8];
        *(uint4*)&Bs[ds] = *(const uint4*)&Bsrc[(size_t)row * NC + seg * 8];
    }
    __syncthreads();
    f32x4 acc[4] = {};
    const int abase = (w * 16 + l16) * 256;
    const int asw = l16 & 7;
    #pragma unroll
    for (int kk = 0; kk < 8; ++kk) {
        const int koff = ((kk * 4 + g) ^ asw) << 3;
        bf16x8 a = *(const bf16x8*)&As[abase + koff];
        #pragma unroll
        for (int j = 0; j < 4; ++j) {
            bf16x8 b = *(const bf16x8*)&Bs[(j * 16 + l16) * 256 + koff];
            acc[j] = __builtin_amdgcn_mfma_f32_16x16x32_bf16(a, b, acc[j], 0, 0, 0);
        }
    }
    const int b = (int)(prow0 >> 10);
    const int pp = (int)(prow0 & 1023);
    if (MODE == 0) {
        int ob_ = o0 + 16 * w + 4 * g;
        int n = ob_ >> 5, d0 = ob_ & 31;
        unsigned short* dst = (unsigned short*)out0 + ((size_t)(b * NHEAD + n) * HWSZ) * DHEAD + d0;
        #pragma unroll
        for (int j = 0; j < 4; ++j) {
            int p = pp + 16 * j + l16;
            uint2 st;
            st.x = pk2(acc[j][0], acc[j][1]);
            st.y = pk2(acc[j][2], acc[j][3]);
            *(uint2*)&dst[(size_t)p * DHEAD] = st;
        }
    } else if (MODE == 1) {
        int n = o0 >> 6;
        int d0 = 16 * (w & 1) + 4 * g;
        if (w < 2) {   // K
            unsigned short* dst = (unsigned short*)out0 + ((size_t)(b * NHEAD + n) * HWSZ) * DHEAD + d0;
            #pragma unroll
            for (int j = 0; j < 4; ++j) {
                int p = pp + 16 * j + l16;
                uint2 st;
                st.x = pk2(acc[j][0], acc[j][1]);
                st.y = pk2(acc[j][2], acc[j][3]);
                *(uint2*)&dst[(size_t)p * DHEAD] = st;
            }
        } else {
            // V -> [b][n][d][p'] with sigma-permuted key order within each
            // 32-key block: key k32 = 16*(j&1)+l16 stored at slot
            // 8*(l16>>2) + 4*(j&1) + (l16&3), so attention's PV A-fragment
            // (kslots 8g..8g+7) is one contiguous 16B load.
            unsigned short* dst = (unsigned short*)out1 + ((size_t)(b * NHEAD + n) * DHEAD + d0) * HWSZ;
            #pragma unroll
            for (int j = 0; j < 4; ++j) {
                int slot = ((l16 >> 2) << 3) + ((j & 1) << 2) + (l16 & 3);
                int p = pp + 32 * (j >> 1) + slot;
                #pragma unroll
                for (int r = 0; r < 4; ++r)
                    dst[(size_t)r * HWSZ + p] = f2bf(acc[j][r]);
            }
        }
    } else {
        int p_b = pp + 16 * w + 4 * g;
        #pragma unroll
        for (int j = 0; j < 4; ++j) {
            int o = o0 + 16 * j + l16;
            float bo = bias_out[o];
            size_t off = ((size_t)b * NC + o) * HWSZ + p_b;
            float4 rs = *(const float4*)&resid[off];
            float4 vst = make_float4(acc[j][0] + bo + rs.x, acc[j][1] + bo + rs.y,
                                     acc[j][2] + bo + rs.z, acc[j][3] + bo + rs.w);
            *(float4*)&((float*)out0)[off] = vst;
        }
    }
}

// ---------------- MFMA flash attention, zero-LDS, shuffle-free steady state ----
// P never leaves registers (sigma k-perm on both PV operands). l accumulated
// PER-LANE (each lane owns a fixed sigma-subset of keys), reduced once in the
// epilogue. Defer-max guard uses per-lane partial maxes via __all (equivalent
// as a bound check); cross-lane max reduce only on the rare trigger.
__global__ __launch_bounds__(256) void attn_mfma_kernel(
        const unsigned short* __restrict__ qb,
        const unsigned short* __restrict__ kb,
        const unsigned short* __restrict__ vb,
        unsigned short* __restrict__ ob) {
    const int tid = threadIdx.x;
    const int lane = tid & 63;
    const int l16 = lane & 15, g = lane >> 4;
    const int bn = blockIdx.y;
    const int qp = blockIdx.x * 64 + (tid >> 6) * 16 + l16;

    bf16x8 qf = *(const bf16x8*)(qb + ((size_t)bn * HWSZ + qp) * DHEAD + g * 8);
    const unsigned short* kbase = kb + (size_t)bn * HWSZ * DHEAD + (size_t)l16 * DHEAD + g * 8;
    const unsigned short* v_lo = vb + (size_t)bn * DHEAD * HWSZ + (size_t)l16 * HWSZ + 8 * g;
    const unsigned short* v_hi = v_lo + 16 * HWSZ;

    f32x4 acc0 = {0.f, 0.f, 0.f, 0.f}, acc1 = {0.f, 0.f, 0.f, 0.f};
    float m = -INFINITY;
    float l0 = 0.f, l1 = 0.f;   // per-lane partial softmax denominators

#define LOADK_A(kt) (*(const bf16x8*)(kbase + (kt) * 32 * DHEAD))
#define LOADK_B(kt) (*(const bf16x8*)(kbase + (kt) * 32 * DHEAD + 16 * DHEAD))
#define LOADV_A(kt) (*(const bf16x8*)(v_lo + (kt) * 32))
#define LOADV_B(kt) (*(const bf16x8*)(v_hi + (kt) * 32))

    bf16x8 ka0 = LOADK_A(0), kb0 = LOADK_B(0), va0 = LOADV_A(0), vb0 = LOADV_B(0);
    bf16x8 ka1 = LOADK_A(1), kb1 = LOADK_B(1), va1 = LOADV_A(1), vb1 = LOADV_B(1);

    #pragma unroll
    for (int kt = 0; kt < 32; ++kt) {
        bf16x8 nka = ka1, nkb = kb1, nva = va1, nvb = vb1;
        if (kt + 2 < 32) {
            nka = LOADK_A(kt + 2); nkb = LOADK_B(kt + 2);
            nva = LOADV_A(kt + 2); nvb = LOADV_B(kt + 2);
        }

        f32x4 z = {0.f, 0.f, 0.f, 0.f};
        f32x4 s0 = __builtin_amdgcn_mfma_f32_16x16x32_bf16(ka0, qf, z, 0, 0, 0);
        f32x4 s1 = __builtin_amdgcn_mfma_f32_16x16x32_bf16(kb0, qf, z, 0, 0, 0);

        // per-lane partial max (no cross-lane ops in steady state)
        float tm = fmaxf(fmaxf(fmaxf(s0[0], s0[1]), fmaxf(s0[2], s0[3])),
                         fmaxf(fmaxf(s1[0], s1[1]), fmaxf(s1[2], s1[3])));
        // defer-max guard: if every lane's partial max is within m+8, the true
        // max is too. Wave-uniform branch; triggers on tile 0 and then rarely.
        if (!__all(tm <= m + 8.f)) {
            float tmr = fmaxf(tm, __shfl_xor(tm, 16, 64));
            tmr = fmaxf(tmr, __shfl_xor(tmr, 32, 64));
            float mnew = fmaxf(m, tmr);
            float corr = __builtin_amdgcn_exp2f(m - mnew);  // tile 0: 2^-inf = 0
            acc0 *= corr; acc1 *= corr; l0 *= corr; l1 *= corr;
            m = mnew;
        }
        float p00 = __builtin_amdgcn_exp2f(s0[0] - m), p01 = __builtin_amdgcn_exp2f(s0[1] - m);
        float p02 = __builtin_amdgcn_exp2f(s0[2] - m), p03 = __builtin_amdgcn_exp2f(s0[3] - m);
        float p10 = __builtin_amdgcn_exp2f(s1[0] - m), p11 = __builtin_amdgcn_exp2f(s1[1] - m);
        float p12 = __builtin_amdgcn_exp2f(s1[2] - m), p13 = __builtin_amdgcn_exp2f(s1[3] - m);
        l0 += (p00 + p01) + (p02 + p03);
        l1 += (p10 + p11) + (p12 + p13);

        // B-frag: keys in sigma order, straight from registers
        uint4 pw;
        pw.x = pk2(p00, p01); pw.y = pk2(p02, p03);
        pw.z = pk2(p10, p11); pw.w = pk2(p12, p13);
        bf16x8 pf;
        memcpy(&pf, &pw, sizeof(pf));

        acc0 = __builtin_amdgcn_mfma_f32_16x16x32_bf16(va0, pf, acc0, 0, 0, 0);
        acc1 = __builtin_amdgcn_mfma_f32_16x16x32_bf16(vb0, pf, acc1, 0, 0, 0);

        ka0 = ka1; kb0 = kb1; va0 = va1; vb0 = vb1;
        ka1 = nka; kb1 = nkb; va1 = nva; vb1 = nvb;
    }
#undef LOADK_A
#undef LOADK_B
#undef LOADV_A
#undef LOADV_B

    // epilogue: one cross-lane reduce for l (lanes of a query group differ in
    // bits 4..5 of the lane id)
    float l = l0 + l1;
    l += __shfl_xor(l, 16, 64);
    l += __shfl_xor(l, 32, 64);
    float invl = 1.f / l;

    const int b = bn >> 3, n = bn & 7;
    unsigned short* dst = ob + ((size_t)b * HWSZ + qp) * NC + n * DHEAD;
    uint2 st0, st1;
    st0.x = pk2(acc0[0] * invl, acc0[1] * invl);
    st0.y = pk2(acc0[2] * invl, acc0[3] * invl);
    st1.x = pk2(acc1[0] * invl, acc1[1] * invl);
    st1.y = pk2(acc1[2] * invl, acc1[3] * invl);
    *(uint2*)&dst[4 * g]      = st0;
    *(uint2*)&dst[16 + 4 * g] = st1;
}

extern "C" void kernel_launch(void* const* d_in, const int* in_sizes, int n_in,
                              void* d_out, int out_size, void* d_ws, size_t ws_size,
                              hipStream_t stream) {
    const float* input_q  = (const float*)d_in[0];
    const float* input_kv = (const float*)d_in[1];
    const float* gq_scale = (const float*)d_in[2];
    const float* gq_bias  = (const float*)d_in[3];
    const float* gkv_scale = (const float*)d_in[4];
    const float* gkv_bias  = (const float*)d_in[5];
    const float* Wq   = (const float*)d_in[6];
    const float* Wkv  = (const float*)d_in[7];
    const float* Wout = (const float*)d_in[8];
    const float* bout = (const float*)d_in[9];
    float* out = (float*)d_out;

    char* ws = (char*)d_ws;
    float* stats = (float*)ws;                                    // 8 KB
    unsigned short* wqb   = (unsigned short*)(ws + 16384);        // 128 KB
    unsigned short* wkvb  = (unsigned short*)(ws + 16384 + 131072);        // 256 KB
    unsigned short* woutb = (unsigned short*)(ws + 16384 + 131072 + 262144); // 128 KB
    const size_t MB = 1024 * 1024;
    unsigned short* xnq  = (unsigned short*)(ws + 1 * MB);   // 4 MB  [b][p][c]
    unsigned short* xnkv = (unsigned short*)(ws + 5 * MB);   // 4 MB
    unsigned short* qbuf = (unsigned short*)(ws + 9 * MB);   // 4 MB  [b][n][p][d]
    unsigned short* kbuf = (unsigned short*)(ws + 13 * MB);  // 4 MB  [b][n][p][d]
    unsigned short* vbuf = (unsigned short*)(ws + 17 * MB);  // 4 MB  [b][n][d][p'] sigma-permuted
    unsigned short* obuf = (unsigned short*)(ws + 21 * MB);  // 4 MB  [b][p][c]

    gn_stats_kernel<<<512, 256, 0, stream>>>(input_q, input_kv, stats);
    wconv_kernel<<<128, 256, 0, stream>>>(Wq, Wkv, Wout, wqb, wkvb, woutb);
    norm_t_kernel<<<dim3(16, 4, 16), 256, 0, stream>>>(
        input_q, input_kv, stats, gq_scale, gq_bias, gkv_scale, gkv_bias, xnq, xnkv);
    gemm_kernel<0><<<dim3(128, 4), 256, 0, stream>>>(wqb, xnq, nullptr, nullptr, qbuf, nullptr);
    gemm_kernel<1><<<dim3(128, 8), 256, 0, stream>>>(wkvb, xnkv, nullptr, nullptr, kbuf, vbuf);
    attn_mfma_kernel<<<dim3(16, 64), 256, 0, stream>>>(qbuf, kbuf, vbuf, obuf);
    gemm_kernel<2><<<dim3(128, 4), 256, 0, stream>>>(obuf, woutb, bout, input_q, out, nullptr);
}

// Round 9
// 61.409 us; speedup vs baseline: 1.7472x; 1.2990x over previous
//
#include <hip/hip_runtime.h>
#include <hip/hip_bf16.h>
#include <math.h>
#include <string.h>

#define NB 8
#define NC 256
#define HWSZ 1024
#define NHEAD 8
#define DHEAD 32
#define NGRP 32
#define CPG 8
#define EPSV 1e-5f

typedef float f32x4 __attribute__((ext_vector_type(4)));
typedef short bf16x8 __attribute__((ext_vector_type(8)));

__device__ __forceinline__ unsigned pk2(float a, float b) {
    __hip_bfloat162 h = __float22bfloat162_rn(make_float2(a, b));
    unsigned r;
    memcpy(&r, &h, sizeof(r));
    return r;
}
__device__ __forceinline__ unsigned short f2bf(float x) {
    __hip_bfloat16 h = __float2bfloat16(x);
    unsigned short r;
    memcpy(&r, &h, sizeof(r));
    return r;
}

// ---------------- GroupNorm stats ----------------
__global__ void gn_stats_kernel(const float* __restrict__ xq,
                                const float* __restrict__ xkv,
                                float* __restrict__ stats) {
    int idx = blockIdx.x;            // which*256 + b*32 + g
    int which = idx >> 8;
    int b = (idx >> 5) & 7;
    int g = idx & 31;
    const float* x = which ? xkv : xq;
    const float4* xb = (const float4*)(x + ((size_t)(b * NC + g * CPG)) * HWSZ);
    float s = 0.f, ss = 0.f;
    for (int i = threadIdx.x; i < (CPG * HWSZ) / 4; i += 256) {
        float4 v = xb[i];
        s += v.x + v.y + v.z + v.w;
        ss += v.x * v.x + v.y * v.y + v.z * v.z + v.w * v.w;
    }
    #pragma unroll
    for (int off = 32; off > 0; off >>= 1) {
        s += __shfl_down(s, off);
        ss += __shfl_down(ss, off);
    }
    __shared__ float red[8];
    int wid = threadIdx.x >> 6;
    if ((threadIdx.x & 63) == 0) { red[wid * 2] = s; red[wid * 2 + 1] = ss; }
    __syncthreads();
    if (threadIdx.x == 0) {
        float S = red[0] + red[2] + red[4] + red[6];
        float SS = red[1] + red[3] + red[5] + red[7];
        float mean = S * (1.f / (CPG * HWSZ));
        float var = SS * (1.f / (CPG * HWSZ)) - mean * mean;
        stats[idx * 2] = mean;
        stats[idx * 2 + 1] = rsqrtf(var + EPSV);
    }
}

// ---------------- Weight convert: fp32 [o][c] -> bf16 [o][c]; Wq pre-scaled ----
__global__ void wconv_kernel(const float* __restrict__ Wq,
                             const float* __restrict__ Wkv,
                             const float* __restrict__ Wout,
                             unsigned short* __restrict__ wqb,
                             unsigned short* __restrict__ wkvb,
                             unsigned short* __restrict__ woutb) {
    int gid = blockIdx.x * 256 + threadIdx.x;   // 32768 threads, 8 floats each
    int i0 = gid * 8;
    const float* src; unsigned short* dst; int off; float sc = 1.f;
    if (i0 < 65536)       { src = Wq;   dst = wqb;   off = i0;          sc = 0.0625f * 1.44269504088896f; }
    else if (i0 < 196608) { src = Wkv;  dst = wkvb;  off = i0 - 65536; }
    else                  { src = Wout; dst = woutb; off = i0 - 196608; }
    float4 v0 = *(const float4*)&src[off];
    float4 v1 = *(const float4*)&src[off + 4];
    uint4 o;
    o.x = pk2(v0.x * sc, v0.y * sc); o.y = pk2(v0.z * sc, v0.w * sc);
    o.z = pk2(v1.x * sc, v1.y * sc); o.w = pk2(v1.z * sc, v1.w * sc);
    *(uint4*)&dst[off] = o;
}

// ---------------- Norm + bf16 + transpose: x fp32 [b][c][p] -> xn bf16 [b][p][c] ----
__global__ __launch_bounds__(256) void norm_t_kernel(
        const float* __restrict__ xq, const float* __restrict__ xkv,
        const float* __restrict__ stats,
        const float* __restrict__ sq, const float* __restrict__ bq,
        const float* __restrict__ skv, const float* __restrict__ bkv,
        unsigned short* __restrict__ xnq, unsigned short* __restrict__ xnkv) {
    __shared__ unsigned short T[64][72];   // [p][c], 144B rows
    const int bz = blockIdx.z;             // which*8 + b
    const int which = bz >> 3, b = bz & 7;
    const int c0 = blockIdx.y * 64, p0 = blockIdx.x * 64;
    const float* x  = which ? xkv : xq;
    const float* sc = which ? skv : sq;
    const float* bi = which ? bkv : bq;
    const float* st = stats + ((size_t)which * 256 + b * 32) * 2;
    const int tid = threadIdx.x;
    const int cb = tid >> 4, pb = tid & 15;
    float mm[4][4];
    #pragma unroll
    for (int u = 0; u < 4; ++u) {
        int c = c0 + cb * 4 + u;
        float4 v = *(const float4*)&x[((size_t)b * NC + c) * HWSZ + p0 + pb * 4];
        int gg = c >> 3;
        float mean = st[gg * 2], rstd = st[gg * 2 + 1];
        float a = rstd * sc[c];
        float bbv = bi[c] - mean * a;
        mm[u][0] = v.x * a + bbv; mm[u][1] = v.y * a + bbv;
        mm[u][2] = v.z * a + bbv; mm[u][3] = v.w * a + bbv;
    }
    #pragma unroll
    for (int v = 0; v < 4; ++v) {
        uint2 s2;
        s2.x = pk2(mm[0][v], mm[1][v]);
        s2.y = pk2(mm[2][v], mm[3][v]);
        *(uint2*)&T[pb * 4 + v][cb * 4] = s2;
    }
    __syncthreads();
    unsigned short* dst = (which ? xnkv : xnq) + (size_t)b * HWSZ * NC;
    #pragma unroll
    for (int it = 0; it < 2; ++it) {
        int i = tid + it * 256;
        int row = i >> 3, seg = i & 7;
        *(uint4*)&dst[(size_t)(p0 + row) * NC + c0 + seg * 8] = *(const uint4*)&T[row][seg * 8];
    }
}

// ---------------- MFMA GEMM over K=256, 64x64 tile, 4 waves ----------------
// MODE 0: Q  = Wq(A) x xnq(B)  -> qbuf bf16 [b][n][p][d]
// MODE 1: KV = Wkv(A) x xnkv(B)-> kbuf [b][n][p][d] (waves 0,1) / vbuf sigma-permuted
// MODE 2: OUT = obuf(A, rows p) x Wout(B, rows o) -> f32 d_out + bias + residual
template<int MODE>
__global__ __launch_bounds__(256) void gemm_kernel(
        const unsigned short* __restrict__ Abase,
        const unsigned short* __restrict__ Bbase,
        const float* __restrict__ bias_out,
        const float* __restrict__ resid,
        void* __restrict__ out0, void* __restrict__ out1) {
    __shared__ unsigned short As[64 * 256];
    __shared__ unsigned short Bs[64 * 256];
    const int tid = threadIdx.x;
    const int l16 = tid & 15, g = (tid >> 4) & 3, w = tid >> 6;
    const int o0 = blockIdx.y * 64;
    const size_t prow0 = (size_t)blockIdx.x * 64;
    const unsigned short* Asrc = (MODE < 2) ? (Abase + (size_t)o0 * NC) : (Abase + prow0 * NC);
    const unsigned short* Bsrc = (MODE < 2) ? (Bbase + prow0 * NC) : (Bbase + (size_t)o0 * NC);
    #pragma unroll
    for (int it = 0; it < 8; ++it) {
        int idx = tid + it * 256;
        int row = idx >> 5, seg = idx & 31;
        int ds = row * 256 + ((seg ^ (row & 7)) << 3);   // XOR-swizzled 16B units
        *(uint4*)&As[ds] = *(const uint4*)&Asrc[(size_t)row * NC + seg * 8];
        *(uint4*)&Bs[ds] = *(const uint4*)&Bsrc[(size_t)row * NC + seg * 8];
    }
    __syncthreads();
    f32x4 acc[4] = {};
    const int abase = (w * 16 + l16) * 256;
    const int asw = l16 & 7;
    #pragma unroll
    for (int kk = 0; kk < 8; ++kk) {
        const int koff = ((kk * 4 + g) ^ asw) << 3;
        bf16x8 a = *(const bf16x8*)&As[abase + koff];
        #pragma unroll
        for (int j = 0; j < 4; ++j) {
            bf16x8 b = *(const bf16x8*)&Bs[(j * 16 + l16) * 256 + koff];
            acc[j] = __builtin_amdgcn_mfma_f32_16x16x32_bf16(a, b, acc[j], 0, 0, 0);
        }
    }
    const int b = (int)(prow0 >> 10);
    const int pp = (int)(prow0 & 1023);
    if (MODE == 0) {
        int ob_ = o0 + 16 * w + 4 * g;
        int n = ob_ >> 5, d0 = ob_ & 31;
        unsigned short* dst = (unsigned short*)out0 + ((size_t)(b * NHEAD + n) * HWSZ) * DHEAD + d0;
        #pragma unroll
        for (int j = 0; j < 4; ++j) {
            int p = pp + 16 * j + l16;
            uint2 st;
            st.x = pk2(acc[j][0], acc[j][1]);
            st.y = pk2(acc[j][2], acc[j][3]);
            *(uint2*)&dst[(size_t)p * DHEAD] = st;
        }
    } else if (MODE == 1) {
        int n = o0 >> 6;
        int d0 = 16 * (w & 1) + 4 * g;
        if (w < 2) {   // K
            unsigned short* dst = (unsigned short*)out0 + ((size_t)(b * NHEAD + n) * HWSZ) * DHEAD + d0;
            #pragma unroll
            for (int j = 0; j < 4; ++j) {
                int p = pp + 16 * j + l16;
                uint2 st;
                st.x = pk2(acc[j][0], acc[j][1]);
                st.y = pk2(acc[j][2], acc[j][3]);
                *(uint2*)&dst[(size_t)p * DHEAD] = st;
            }
        } else {
            // V -> [b][n][d][p'] sigma-permuted within each 32-key block:
            // key k32 = 16*(j&1)+l16 stored at slot 8*(l16>>2)+4*(j&1)+(l16&3)
            unsigned short* dst = (unsigned short*)out1 + ((size_t)(b * NHEAD + n) * DHEAD + d0) * HWSZ;
            #pragma unroll
            for (int j = 0; j < 4; ++j) {
                int slot = ((l16 >> 2) << 3) + ((j & 1) << 2) + (l16 & 3);
                int p = pp + 32 * (j >> 1) + slot;
                #pragma unroll
                for (int r = 0; r < 4; ++r)
                    dst[(size_t)r * HWSZ + p] = f2bf(acc[j][r]);
            }
        }
    } else {
        int p_b = pp + 16 * w + 4 * g;
        #pragma unroll
        for (int j = 0; j < 4; ++j) {
            int o = o0 + 16 * j + l16;
            float bo = bias_out[o];
            size_t off = ((size_t)b * NC + o) * HWSZ + p_b;
            float4 rs = *(const float4*)&resid[off];
            float4 vst = make_float4(acc[j][0] + bo + rs.x, acc[j][1] + bo + rs.y,
                                     acc[j][2] + bo + rs.z, acc[j][3] + bo + rs.w);
            *(float4*)&((float*)out0)[off] = vst;
        }
    }
}

// ---------------- MFMA flash attention: block-shared LDS K/V, T14 async stage ----
// 4 waves/block share the 32-key K/V tile via LDS (double-buffered, 4KB each).
// T14 split: issue tile kt+1's global load -> compute kt from LDS -> ds_write
// kt+1 -> barrier. Chunk-rotation swizzle (phys=(chunk+(row>>1))&3) applied on
// the GLOBAL source side keeps LDS writes linear and makes all ds_read_b128
// fragments bank-conflict-free. XCD swizzle: all 16 q-blocks of one bn on the
// same XCD -> K/V L2-resident (1MB/XCD).
__global__ __launch_bounds__(256, 4) void attn_mfma_kernel(
        const unsigned short* __restrict__ qb,
        const unsigned short* __restrict__ kb,
        const unsigned short* __restrict__ vb,
        unsigned short* __restrict__ ob) {
    __shared__ unsigned short KV[2][2048];   // [buf][K:0..1023 | V:1024..2047]
    const int tid = threadIdx.x;
    const int lane = tid & 63;
    const int l16 = lane & 15, g = lane >> 4;

    // XCD swizzle (bijective, grid=1024): xcd = F&7 owns bn in [xcd*8, xcd*8+8)
    const int F = blockIdx.y * 16 + blockIdx.x;
    const int bn = (F & 7) * 8 + (F >> 7);
    const int qblk = (F >> 3) & 15;
    const int qp = qblk * 64 + (tid >> 6) * 16 + l16;

    bf16x8 qf = *(const bf16x8*)(qb + ((size_t)bn * HWSZ + qp) * DHEAD + g * 8);

    // staging map: thread t copies one 16B chunk/tile. t<128: K, else V.
    const int si = tid & 127;
    const int srow = si >> 2;             // key row (K) or d row (V)
    const int pc = si & 3;                // physical chunk in LDS
    const int lc = (pc - (srow >> 1)) & 3; // logical chunk in global
    const unsigned short* sbase;
    int sstep;
    if (tid < 128) {
        sbase = kb + (size_t)bn * HWSZ * DHEAD + (size_t)srow * DHEAD + lc * 8;
        sstep = 32 * DHEAD;               // advance 32 key rows per tile
    } else {
        sbase = vb + (size_t)bn * DHEAD * HWSZ + (size_t)srow * HWSZ + lc * 8;
        sstep = 32;                       // advance 32 key columns per tile
    }
    unsigned short* sd0 = &KV[0][tid * 8];
    unsigned short* sd1 = &KV[1][tid * 8];

    // fragment read offsets (ushort units); rows l16 and l16+16 share phys
    const int phys = (g + (l16 >> 1)) & 3;
    const int koffA = l16 * 32 + phys * 8;
    const int koffB = (l16 + 16) * 32 + phys * 8;

    f32x4 acc0 = {0.f, 0.f, 0.f, 0.f}, acc1 = {0.f, 0.f, 0.f, 0.f};
    float m = -INFINITY;
    float l0 = 0.f, l1 = 0.f;

    *(uint4*)sd0 = *(const uint4*)sbase;   // stage tile 0
    __syncthreads();

    #pragma unroll
    for (int kt = 0; kt < 32; ++kt) {
        const int cur = kt & 1;
        // T14: issue next tile's global load before computing this one
        uint4 nreg;
        if (kt + 1 < 32)
            nreg = *(const uint4*)(sbase + (size_t)(kt + 1) * sstep);

        const unsigned short* bufp = &KV[cur][0];
        bf16x8 ka  = *(const bf16x8*)(bufp + koffA);
        bf16x8 kbf = *(const bf16x8*)(bufp + koffB);
        bf16x8 va  = *(const bf16x8*)(bufp + 1024 + koffA);
        bf16x8 vbf = *(const bf16x8*)(bufp + 1024 + koffB);

        f32x4 z = {0.f, 0.f, 0.f, 0.f};
        f32x4 s0 = __builtin_amdgcn_mfma_f32_16x16x32_bf16(ka,  qf, z, 0, 0, 0);
        f32x4 s1 = __builtin_amdgcn_mfma_f32_16x16x32_bf16(kbf, qf, z, 0, 0, 0);

        // per-lane partial max; defer-max guard (cross-lane only on trigger)
        float tm = fmaxf(fmaxf(fmaxf(s0[0], s0[1]), fmaxf(s0[2], s0[3])),
                         fmaxf(fmaxf(s1[0], s1[1]), fmaxf(s1[2], s1[3])));
        if (!__all(tm <= m + 8.f)) {
            float tmr = fmaxf(tm, __shfl_xor(tm, 16, 64));
            tmr = fmaxf(tmr, __shfl_xor(tmr, 32, 64));
            float mnew = fmaxf(m, tmr);
            float corr = __builtin_amdgcn_exp2f(m - mnew);  // tile 0: 2^-inf = 0
            acc0 *= corr; acc1 *= corr; l0 *= corr; l1 *= corr;
            m = mnew;
        }
        float p00 = __builtin_amdgcn_exp2f(s0[0] - m), p01 = __builtin_amdgcn_exp2f(s0[1] - m);
        float p02 = __builtin_amdgcn_exp2f(s0[2] - m), p03 = __builtin_amdgcn_exp2f(s0[3] - m);
        float p10 = __builtin_amdgcn_exp2f(s1[0] - m), p11 = __builtin_amdgcn_exp2f(s1[1] - m);
        float p12 = __builtin_amdgcn_exp2f(s1[2] - m), p13 = __builtin_amdgcn_exp2f(s1[3] - m);
        l0 += (p00 + p01) + (p02 + p03);
        l1 += (p10 + p11) + (p12 + p13);

        uint4 pw;
        pw.x = pk2(p00, p01); pw.y = pk2(p02, p03);
        pw.z = pk2(p10, p11); pw.w = pk2(p12, p13);
        bf16x8 pf;
        memcpy(&pf, &pw, sizeof(pf));

        acc0 = __builtin_amdgcn_mfma_f32_16x16x32_bf16(va,  pf, acc0, 0, 0, 0);
        acc1 = __builtin_amdgcn_mfma_f32_16x16x32_bf16(vbf, pf, acc1, 0, 0, 0);

        // write the staged tile kt+1 into the other buffer, then sync
        if (kt + 1 < 32)
            *(uint4*)(cur ? sd0 : sd1) = nreg;
        __syncthreads();
    }

    // epilogue: single cross-lane reduce of the softmax denominator
    float l = l0 + l1;
    l += __shfl_xor(l, 16, 64);
    l += __shfl_xor(l, 32, 64);
    float invl = 1.f / l;

    const int b = bn >> 3, n = bn & 7;
    unsigned short* dst = ob + ((size_t)b * HWSZ + qp) * NC + n * DHEAD;
    uint2 st0, st1;
    st0.x = pk2(acc0[0] * invl, acc0[1] * invl);
    st0.y = pk2(acc0[2] * invl, acc0[3] * invl);
    st1.x = pk2(acc1[0] * invl, acc1[1] * invl);
    st1.y = pk2(acc1[2] * invl, acc1[3] * invl);
    *(uint2*)&dst[4 * g]      = st0;
    *(uint2*)&dst[16 + 4 * g] = st1;
}

extern "C" void kernel_launch(void* const* d_in, const int* in_sizes, int n_in,
                              void* d_out, int out_size, void* d_ws, size_t ws_size,
                              hipStream_t stream) {
    const float* input_q  = (const float*)d_in[0];
    const float* input_kv = (const float*)d_in[1];
    const float* gq_scale = (const float*)d_in[2];
    const float* gq_bias  = (const float*)d_in[3];
    const float* gkv_scale = (const float*)d_in[4];
    const float* gkv_bias  = (const float*)d_in[5];
    const float* Wq   = (const float*)d_in[6];
    const float* Wkv  = (const float*)d_in[7];
    const float* Wout = (const float*)d_in[8];
    const float* bout = (const float*)d_in[9];
    float* out = (float*)d_out;

    char* ws = (char*)d_ws;
    float* stats = (float*)ws;                                    // 8 KB
    unsigned short* wqb   = (unsigned short*)(ws + 16384);        // 128 KB
    unsigned short* wkvb  = (unsigned short*)(ws + 16384 + 131072);        // 256 KB
    unsigned short* woutb = (unsigned short*)(ws + 16384 + 131072 + 262144); // 128 KB
    const size_t MB = 1024 * 1024;
    unsigned short* xnq  = (unsigned short*)(ws + 1 * MB);   // 4 MB  [b][p][c]
    unsigned short* xnkv = (unsigned short*)(ws + 5 * MB);   // 4 MB
    unsigned short* qbuf = (unsigned short*)(ws + 9 * MB);   // 4 MB  [b][n][p][d]
    unsigned short* kbuf = (unsigned short*)(ws + 13 * MB);  // 4 MB  [b][n][p][d]
    unsigned short* vbuf = (unsigned short*)(ws + 17 * MB);  // 4 MB  [b][n][d][p'] sigma-permuted
    unsigned short* obuf = (unsigned short*)(ws + 21 * MB);  // 4 MB  [b][p][c]

    gn_stats_kernel<<<512, 256, 0, stream>>>(input_q, input_kv, stats);
    wconv_kernel<<<128, 256, 0, stream>>>(Wq, Wkv, Wout, wqb, wkvb, woutb);
    norm_t_kernel<<<dim3(16, 4, 16), 256, 0, stream>>>(
        input_q, input_kv, stats, gq_scale, gq_bias, gkv_scale, gkv_bias, xnq, xnkv);
    gemm_kernel<0><<<dim3(128, 4), 256, 0, stream>>>(wqb, xnq, nullptr, nullptr, qbuf, nullptr);
    gemm_kernel<1><<<dim3(128, 8), 256, 0, stream>>>(wkvb, xnkv, nullptr, nullptr, kbuf, vbuf);
    attn_mfma_kernel<<<dim3(16, 64), 256, 0, stream>>>(qbuf, kbuf, vbuf, obuf);
    gemm_kernel<2><<<dim3(128, 4), 256, 0, stream>>>(obuf, woutb, bout, input_q, out, nullptr);
}